// Round 8
// baseline (4758.170 us; speedup 1.0000x reference)
//
#include <hip/hip_runtime.h>

typedef _Float16 half_t;
typedef _Float16 half2_t __attribute__((ext_vector_type(2)));
typedef _Float16 half4_t __attribute__((ext_vector_type(4)));
typedef _Float16 half8_t __attribute__((ext_vector_type(8)));
typedef float    floatx4 __attribute__((ext_vector_type(4)));

#define T_SEQ 2048
#define EDIM  512

// workspace layout (bytes). total required ~71.4 MB
static constexpr size_t EMB_OFF = 0;                       // 32*2048*512 f16 = 67,108,864
static constexpr size_t Q_OFF   = 67108864;                // 2048*512 f16 (x16 aliased during LSTM)
static constexpr size_t WQ_OFF  = Q_OFF  + 2097152;
static constexpr size_t WK_OFF  = WQ_OFF + 524288;
static constexpr size_t WV_OFF  = WK_OFF + 524288;
static constexpr size_t WO_OFF  = WV_OFF + 524288;
static constexpr size_t TE_OFF  = WO_OFF + 524288;

__device__ __forceinline__ float fdot2f(half2_t a, half2_t b, float c) {
#if __has_builtin(__builtin_amdgcn_fdot2)
  return __builtin_amdgcn_fdot2(a, b, c, false);
#else
  return c + (float)a[0] * (float)b[0] + (float)a[1] * (float)b[1];
#endif
}
__device__ __forceinline__ half2_t mkh2(float a, float b) {
  half2_t r; r[0] = (half_t)a; r[1] = (half_t)b; return r;
}
__device__ __forceinline__ half2_t h2bc(unsigned u) { return __builtin_bit_cast(half2_t, u); }
__device__ __forceinline__ unsigned h2u(half2_t h)  { return __builtin_bit_cast(unsigned, h); }
__device__ __forceinline__ float sigm(float v)  { return __builtin_amdgcn_rcpf(1.f + __expf(-v)); }
__device__ __forceinline__ float tanhf_(float v){ return __builtin_amdgcn_rcpf(1.f + __expf(-2.f * v)) * 2.f - 1.f; }

// ---------------------------------------------------------------------------
__global__ void convert_kernel(const float* __restrict__ wq, const float* __restrict__ wk,
                               const float* __restrict__ wvv, const float* __restrict__ wo,
                               const float* __restrict__ te, const float* __restrict__ x,
                               half_t* __restrict__ wq16, half_t* __restrict__ wk16,
                               half_t* __restrict__ wv16, half_t* __restrict__ wo16,
                               half_t* __restrict__ te16, half_t* __restrict__ x16) {
  int i4 = (blockIdx.x * 256 + threadIdx.x) * 4;
  const float* src; half_t* dst; int off;
  if      (i4 < 262144)     { src = wq;  dst = wq16; off = i4; }
  else if (i4 < 2 * 262144) { src = wk;  dst = wk16; off = i4 - 262144; }
  else if (i4 < 3 * 262144) { src = wvv; dst = wv16; off = i4 - 2 * 262144; }
  else if (i4 < 4 * 262144) { src = wo;  dst = wo16; off = i4 - 3 * 262144; }
  else if (i4 < 4 * 262144 + 16384) { src = te; dst = te16; off = i4 - 4 * 262144; }
  else                      { src = x;   dst = x16;  off = i4 - (4 * 262144 + 16384); }
  float4 v = *(const float4*)(src + off);
  half4_t h; h[0] = (half_t)v.x; h[1] = (half_t)v.y; h[2] = (half_t)v.z; h[3] = (half_t)v.w;
  *(half4_t*)(dst + off) = h;
}

// ---------------------------------------------------------------------------
// MFMA LSTM. One (branch,dir) chain per block, 512 threads (8 waves, 2/SIMD).
// Gates g[1024] = W_hh(1024x256) h + W_ih x + b computed as MFMA 16x16x32:
// A row0 = h k-chunk (rows 1-15 garbage, never read); B = W_hh^T fragments —
// kc 0..5 resident in registers used ONLY by MFMA -> compiler places in AGPRs,
// which MFMA reads natively (kills R4-R7's v_accvgpr_read-per-weight-use, the
// measured ~2.3x VALU inflation). kc 6,7 + W_ih live in LDS. Per step:
// all waves: init acc reg0 from xw (f16 LDS), 64 MFMA, extract row0 -> gates;
// barrier; waves 0-3: c/h update + emb write; waves 4-7: next-step xw = W_ih x
// (x broadcast in SGPRs via readfirstlane); barrier.
// Gate n = w*128 + nt*16 + l  (l=lane&15). Gate type = n>>8 (i,f,g,o).
#define LSTM_LDS_BYTES (131072 + 24576 + 4096 + 2048 + 1024)  // 162,816 <= 163,840

__global__ __launch_bounds__(512, 1)
void lstm_kernel(const half_t* __restrict__ x16,
                 const float* __restrict__ wih_f, const float* __restrict__ whh_f, const float* __restrict__ b_f,
                 const float* __restrict__ wih_b, const float* __restrict__ whh_b, const float* __restrict__ b_b,
                 half_t* __restrict__ emb) {
  extern __shared__ char smem[];
  char*   whh_lds  = smem;                                        // [8w][2c][8nt][64 lane x16B]
  half_t* wih_lds  = (half_t*)(smem + 131072);                    // [1024 rows][12]
  half_t* xw_lds   = (half_t*)(smem + 131072 + 24576);            // [2][8w][16l][8nt]
  half_t* gate_lds = (half_t*)(smem + 131072 + 24576 + 4096);     // [8w][16l][8nt]
  half_t* hbuf     = (half_t*)(smem + 131072 + 24576 + 4096 + 2048); // [2][256]

  const int bid = blockIdx.x, br = bid >> 1, dir = bid & 1;
  const int tid = threadIdx.x, lane = tid & 63, w = tid >> 6;
  const int cl = lane & 15, kg = lane >> 4;

  const float* wih  = dir ? wih_b : wih_f;
  const float* whh  = dir ? whh_b : whh_f;
  const float* bias = dir ? b_b   : b_f;

  // ---- stage register-resident B fragments (kc 0..5) ----
  half8_t bfrag[6][8];
#pragma unroll
  for (int kc = 0; kc < 6; ++kc)
#pragma unroll
    for (int nt = 0; nt < 8; ++nt) {
      const float* s = whh + ((size_t)br * 1024 + w * 128 + nt * 16 + cl) * 256 + kc * 32 + kg * 8;
      float4 a = *(const float4*)s, b = *(const float4*)(s + 4);
      half8_t h8;
      h8[0] = (half_t)a.x; h8[1] = (half_t)a.y; h8[2] = (half_t)a.z; h8[3] = (half_t)a.w;
      h8[4] = (half_t)b.x; h8[5] = (half_t)b.y; h8[6] = (half_t)b.z; h8[7] = (half_t)b.w;
      bfrag[kc][nt] = h8;
    }
  // ---- stage LDS B fragments (kc 6,7) ----
#pragma unroll
  for (int c = 0; c < 2; ++c)
#pragma unroll
    for (int nt = 0; nt < 8; ++nt) {
      const float* s = whh + ((size_t)br * 1024 + w * 128 + nt * 16 + cl) * 256 + (6 + c) * 32 + kg * 8;
      float4 a = *(const float4*)s, b = *(const float4*)(s + 4);
      half8_t h8;
      h8[0] = (half_t)a.x; h8[1] = (half_t)a.y; h8[2] = (half_t)a.z; h8[3] = (half_t)a.w;
      h8[4] = (half_t)b.x; h8[5] = (half_t)b.y; h8[6] = (half_t)b.z; h8[7] = (half_t)b.w;
      *(half8_t*)(whh_lds + (((w * 2 + c) * 8 + nt) * 64 + lane) * 16) = h8;
    }
  // ---- stage W_ih rows (f16, 12/row = 24B rows, 8B-aligned writes) ----
#pragma unroll
  for (int rr = 0; rr < 2; ++rr) {
    const int row = tid * 2 + rr;
    const float* s = wih + ((size_t)br * 1024 + row) * 12;
    half_t* d = wih_lds + row * 12;
#pragma unroll
    for (int q = 0; q < 3; ++q) {
      float4 v = *(const float4*)(s + q * 4);
      half4_t h4; h4[0] = (half_t)v.x; h4[1] = (half_t)v.y; h4[2] = (half_t)v.z; h4[3] = (half_t)v.w;
      *(half4_t*)(d + q * 4) = h4;
    }
  }
  const int tt = (tid >= 256) ? (tid - 256) : 0;
  float bias4[4];
#pragma unroll
  for (int r = 0; r < 4; ++r) bias4[r] = bias[(size_t)br * 1024 + tt * 4 + r];

  if (tid < 256) { hbuf[tid] = (half_t)0.f; hbuf[256 + tid] = (half_t)0.f; }

  // x for step 0 (uniform -> sgpr)
  unsigned xs0, xs1, xs2, xs3, xs4, xs5;
  {
    const int t0 = dir ? 2047 : 0;
    const unsigned* xp = (const unsigned*)(x16 + ((size_t)br * T_SEQ + t0) * 12);
    xs0 = __builtin_amdgcn_readfirstlane(xp[0]); xs1 = __builtin_amdgcn_readfirstlane(xp[1]);
    xs2 = __builtin_amdgcn_readfirstlane(xp[2]); xs3 = __builtin_amdgcn_readfirstlane(xp[3]);
    xs4 = __builtin_amdgcn_readfirstlane(xp[4]); xs5 = __builtin_amdgcn_readfirstlane(xp[5]);
  }
  __syncthreads();

  // prologue: waves 4-7 compute xw for step 0 into buffer 0
  if (tid >= 256) {
    float p[4] = { bias4[0], bias4[1], bias4[2], bias4[3] };
    half2_t xp2[6] = { h2bc(xs0), h2bc(xs1), h2bc(xs2), h2bc(xs3), h2bc(xs4), h2bc(xs5) };
#pragma unroll
    for (int r = 0; r < 4; ++r) {
      const half_t* wr = wih_lds + (tt * 4 + r) * 12;
#pragma unroll
      for (int q = 0; q < 3; ++q) {
        uint2 u = *(const uint2*)(wr + q * 4);
        p[r] = fdot2f(h2bc(u.x), xp2[2 * q], p[r]);
        p[r] = fdot2f(h2bc(u.y), xp2[2 * q + 1], p[r]);
      }
    }
#pragma unroll
    for (int r = 0; r < 4; ++r) {
      const int nn = tt * 4 + r;
      xw_lds[((nn >> 7) * 16 + (nn & 15)) * 8 + ((nn >> 4) & 7)] = (half_t)p[r];
    }
  }
  // set xs = x(tin(1)), start xd = x(tin(2)) pipeline
  unsigned xd0, xd1, xd2, xd3, xd4, xd5;
  {
    const int q1 = dir ? 2046 : 1, q2 = dir ? 2045 : 2;
    const unsigned* p1 = (const unsigned*)(x16 + ((size_t)br * T_SEQ + q1) * 12);
    const unsigned* p2 = (const unsigned*)(x16 + ((size_t)br * T_SEQ + q2) * 12);
    xs0 = __builtin_amdgcn_readfirstlane(p1[0]); xs1 = __builtin_amdgcn_readfirstlane(p1[1]);
    xs2 = __builtin_amdgcn_readfirstlane(p1[2]); xs3 = __builtin_amdgcn_readfirstlane(p1[3]);
    xs4 = __builtin_amdgcn_readfirstlane(p1[4]); xs5 = __builtin_amdgcn_readfirstlane(p1[5]);
    xd0 = p2[0]; xd1 = p2[1]; xd2 = p2[2]; xd3 = p2[3]; xd4 = p2[4]; xd5 = p2[5];
  }
  __syncthreads();

  floatx4 acc[8];
#pragma unroll
  for (int nt = 0; nt < 8; ++nt) acc[nt] = floatx4{0.f, 0.f, 0.f, 0.f};
  float cst = 0.f;

#pragma unroll 1
  for (int s = 0; s < T_SEQ; ++s) {
    const int cur = s & 1, nxt = cur ^ 1;

    // phase 1: acc reg0 <- xw (rows 1-15 / lanes>=16 hold junk, never read)
    half8_t xwv = *(const half8_t*)(xw_lds + cur * 1024 + (w * 16 + cl) * 8);
#pragma unroll
    for (int nt = 0; nt < 8; ++nt) acc[nt][0] = (float)xwv[nt];

    // phase 2: 64 MFMA over 8 k-chunks
#pragma unroll
    for (int kc = 0; kc < 6; ++kc) {
      half8_t A = *(const half8_t*)(hbuf + cur * 256 + kc * 32 + kg * 8);
#pragma unroll
      for (int nt = 0; nt < 8; ++nt)
        acc[nt] = __builtin_amdgcn_mfma_f32_16x16x32_f16(A, bfrag[kc][nt], acc[nt], 0, 0, 0);
    }
#pragma unroll
    for (int c = 0; c < 2; ++c) {
      half8_t A = *(const half8_t*)(hbuf + cur * 256 + (6 + c) * 32 + kg * 8);
#pragma unroll
      for (int nt = 0; nt < 8; ++nt) {
        half8_t B = *(const half8_t*)(whh_lds + (((w * 2 + c) * 8 + nt) * 64 + lane) * 16);
        acc[nt] = __builtin_amdgcn_mfma_f32_16x16x32_f16(A, B, acc[nt], 0, 0, 0);
      }
    }

    // phase 3: extract D row0 (lanes 0-15, reg0) -> gates (f16)
    if (lane < 16) {
      half8_t g8;
#pragma unroll
      for (int nt = 0; nt < 8; ++nt) g8[nt] = (half_t)acc[nt][0];
      *(half8_t*)(gate_lds + (w * 16 + cl) * 8) = g8;
    }
    __syncthreads();

    // phase 5
    if (tid < 256) {
      // gate n at gate_lds[((n>>7)*16 + (n&15))*8 + ((n>>4)&7)]
      const int n0 = tid, n1 = tid + 256, n2 = tid + 512, n3 = tid + 768;
      float gi = (float)gate_lds[((n0 >> 7) * 16 + (n0 & 15)) * 8 + ((n0 >> 4) & 7)];
      float gf = (float)gate_lds[((n1 >> 7) * 16 + (n1 & 15)) * 8 + ((n1 >> 4) & 7)];
      float gg = (float)gate_lds[((n2 >> 7) * 16 + (n2 & 15)) * 8 + ((n2 >> 4) & 7)];
      float go = (float)gate_lds[((n3 >> 7) * 16 + (n3 & 15)) * 8 + ((n3 >> 4) & 7)];
      float si = sigm(gi), sf = sigm(gf), tg = tanhf_(gg), so = sigm(go);
      cst = sf * cst + si * tg;
      float h = so * tanhf_(cst);
      half_t hh = (half_t)h;
      hbuf[nxt * 256 + tid] = hh;
      const int tcur = dir ? (2047 - s) : s;
      emb[((size_t)br * T_SEQ + tcur) * EDIM + dir * 256 + tid] = hh;
    } else {
      // xw for step s+1 (x = xs, at tin(s+1))
      float p[4] = { bias4[0], bias4[1], bias4[2], bias4[3] };
      half2_t xp2[6] = { h2bc(xs0), h2bc(xs1), h2bc(xs2), h2bc(xs3), h2bc(xs4), h2bc(xs5) };
#pragma unroll
      for (int r = 0; r < 4; ++r) {
        const half_t* wr = wih_lds + (tt * 4 + r) * 12;
#pragma unroll
        for (int q = 0; q < 3; ++q) {
          uint2 u = *(const uint2*)(wr + q * 4);
          p[r] = fdot2f(h2bc(u.x), xp2[2 * q], p[r]);
          p[r] = fdot2f(h2bc(u.y), xp2[2 * q + 1], p[r]);
        }
      }
#pragma unroll
      for (int r = 0; r < 4; ++r) {
        const int nn = tt * 4 + r;
        xw_lds[nxt * 1024 + ((nn >> 7) * 16 + (nn & 15)) * 8 + ((nn >> 4) & 7)] = (half_t)p[r];
      }
      // rotate pipeline: xs <- xd, issue xd <- x(tin(s+3))
      xs0 = __builtin_amdgcn_readfirstlane(xd0); xs1 = __builtin_amdgcn_readfirstlane(xd1);
      xs2 = __builtin_amdgcn_readfirstlane(xd2); xs3 = __builtin_amdgcn_readfirstlane(xd3);
      xs4 = __builtin_amdgcn_readfirstlane(xd4); xs5 = __builtin_amdgcn_readfirstlane(xd5);
      int q3 = s + 3; if (q3 > 2047) q3 = 2047;
      const int t3 = dir ? (2047 - q3) : q3;
      const unsigned* p3 = (const unsigned*)(x16 + ((size_t)br * T_SEQ + t3) * 12);
      xd0 = p3[0]; xd1 = p3[1]; xd2 = p3[2]; xd3 = p3[3]; xd4 = p3[4]; xd5 = p3[5];
    }
    __syncthreads();
  }
}

// ---------------------------------------------------------------------------
__global__ __launch_bounds__(256, 1)
void qproj_kernel(const half_t* __restrict__ emb, const half_t* __restrict__ wq16,
                  const float* __restrict__ bq, half_t* __restrict__ q_ws) {
  const int t0 = blockIdx.x * 32;
  const int tid = threadIdx.x;
  const int lane = tid & 63, wid = tid >> 6;
  const int col = lane & 15, grp = lane >> 4;

  floatx4 acc[2][8];
#pragma unroll
  for (int nt = 0; nt < 8; ++nt) {
    int eo = wid * 128 + nt * 16 + col;
    float b = bq[eo];
#pragma unroll
    for (int mt = 0; mt < 2; ++mt) { acc[mt][nt][0] = b; acc[mt][nt][1] = b; acc[mt][nt][2] = b; acc[mt][nt][3] = b; }
  }
  for (int kc = 0; kc < 16; ++kc) {
    const int e = kc * 32 + grp * 8;
    half8_t a[2];
#pragma unroll
    for (int mt = 0; mt < 2; ++mt) {
      int trow = t0 + mt * 16 + col;
      a[mt] = *(const half8_t*)(emb + (size_t)trow * EDIM + e);
    }
#pragma unroll
    for (int nt = 0; nt < 8; ++nt) {
      int eo = wid * 128 + nt * 16 + col;
      half8_t bf = *(const half8_t*)(wq16 + (size_t)eo * EDIM + e);
#pragma unroll
      for (int mt = 0; mt < 2; ++mt)
        acc[mt][nt] = __builtin_amdgcn_mfma_f32_16x16x32_f16(a[mt], bf, acc[mt][nt], 0, 0, 0);
    }
  }
#pragma unroll
  for (int mt = 0; mt < 2; ++mt)
#pragma unroll
    for (int nt = 0; nt < 8; ++nt)
#pragma unroll
      for (int r = 0; r < 4; ++r) {
        int trow = t0 + mt * 16 + grp * 4 + r;
        int eo = wid * 128 + nt * 16 + col;
        q_ws[(size_t)trow * EDIM + eo] = (half_t)acc[mt][nt][r];
      }
}

// ---------------------------------------------------------------------------
__global__ __launch_bounds__(256, 1)
void attn_kernel(const half_t* __restrict__ emb, const half_t* __restrict__ q_ws,
                 const half_t* __restrict__ wk16, const half_t* __restrict__ wv16,
                 const half_t* __restrict__ wo16, const half_t* __restrict__ te16,
                 const float* __restrict__ bk, const float* __restrict__ bv,
                 const float* __restrict__ bo, float* __restrict__ out) {
  __shared__ float  scores_lds[128];
  __shared__ float  w_lds[128];
  __shared__ half_t ctx_lds[512];

  const int t = blockIdx.x;
  const int tid = threadIdx.x;
  const int lane = tid & 63, wid = tid >> 6;
  const int col = lane & 15, grp = lane >> 4;

  floatx4 kacc[2][8], vacc[2][8];
#pragma unroll
  for (int nt = 0; nt < 8; ++nt) {
    int eo = wid * 128 + nt * 16 + col;
    float kb = bk[eo], vb = bv[eo];
#pragma unroll
    for (int mt = 0; mt < 2; ++mt) {
      kacc[mt][nt][0] = kb; kacc[mt][nt][1] = kb; kacc[mt][nt][2] = kb; kacc[mt][nt][3] = kb;
      vacc[mt][nt][0] = vb; vacc[mt][nt][1] = vb; vacc[mt][nt][2] = vb; vacc[mt][nt][3] = vb;
    }
  }
  for (int kc = 0; kc < 16; ++kc) {
    const int e = kc * 32 + grp * 8;
    half8_t av[2], ak[2];
#pragma unroll
    for (int mt = 0; mt < 2; ++mt) {
      int branch = mt * 16 + col;
      av[mt] = *(const half8_t*)(emb + ((size_t)branch * T_SEQ + t) * EDIM + e);
      half8_t te = *(const half8_t*)(te16 + (size_t)branch * EDIM + e);
      ak[mt] = av[mt] + te;
    }
#pragma unroll
    for (int nt = 0; nt < 8; ++nt) {
      int eo = wid * 128 + nt * 16 + col;
      half8_t bkf = *(const half8_t*)(wk16 + (size_t)eo * EDIM + e);
      half8_t bvf = *(const half8_t*)(wv16 + (size_t)eo * EDIM + e);
#pragma unroll
      for (int mt = 0; mt < 2; ++mt) {
        kacc[mt][nt] = __builtin_amdgcn_mfma_f32_16x16x32_f16(ak[mt], bkf, kacc[mt][nt], 0, 0, 0);
        vacc[mt][nt] = __builtin_amdgcn_mfma_f32_16x16x32_f16(av[mt], bvf, vacc[mt][nt], 0, 0, 0);
      }
    }
  }

  float spart[8];
#pragma unroll
  for (int i = 0; i < 8; ++i) spart[i] = 0.f;
#pragma unroll
  for (int nt = 0; nt < 8; ++nt) {
    int eo = wid * 128 + nt * 16 + col;
    float qf = (float)q_ws[(size_t)t * EDIM + eo];
#pragma unroll
    for (int mt = 0; mt < 2; ++mt)
#pragma unroll
      for (int r = 0; r < 4; ++r)
        spart[mt * 4 + r] += qf * kacc[mt][nt][r];
  }
#pragma unroll
  for (int i = 0; i < 8; ++i) {
    float v = spart[i];
    v += __shfl_xor(v, 1); v += __shfl_xor(v, 2); v += __shfl_xor(v, 4); v += __shfl_xor(v, 8);
    spart[i] = v;
  }
  const float scale = 0.08838834764831845f;
  if (col == 0) {
#pragma unroll
    for (int mt = 0; mt < 2; ++mt)
#pragma unroll
      for (int r = 0; r < 4; ++r)
        scores_lds[wid * 32 + mt * 16 + grp * 4 + r] = spart[mt * 4 + r] * scale;
  }
  float sc = scores_lds[wid * 32 + (lane & 31)];
  float m = sc;
  m = fmaxf(m, __shfl_xor(m, 1));  m = fmaxf(m, __shfl_xor(m, 2));
  m = fmaxf(m, __shfl_xor(m, 4));  m = fmaxf(m, __shfl_xor(m, 8));
  m = fmaxf(m, __shfl_xor(m, 16));
  float ex = __expf(sc - m);
  float sm = ex;
  sm += __shfl_xor(sm, 1); sm += __shfl_xor(sm, 2); sm += __shfl_xor(sm, 4);
  sm += __shfl_xor(sm, 8); sm += __shfl_xor(sm, 16);
  float wn = ex * __builtin_amdgcn_rcpf(sm);
  if (lane < 32) w_lds[wid * 32 + lane] = wn;

  float wb[8];
#pragma unroll
  for (int mt = 0; mt < 2; ++mt)
#pragma unroll
    for (int r = 0; r < 4; ++r)
      wb[mt * 4 + r] = w_lds[wid * 32 + mt * 16 + grp * 4 + r];
#pragma unroll
  for (int nt = 0; nt < 8; ++nt) {
    float cx = 0.f;
#pragma unroll
    for (int mt = 0; mt < 2; ++mt)
#pragma unroll
      for (int r = 0; r < 4; ++r)
        cx += wb[mt * 4 + r] * vacc[mt][nt][r];
    cx += __shfl_xor(cx, 16);
    cx += __shfl_xor(cx, 32);
    float cxh = __shfl_xor(cx, 1);
    if ((lane < 16) && ((lane & 1) == 0))
      *(half2_t*)(ctx_lds + wid * 128 + nt * 16 + lane) = mkh2(cx, cxh);
  }
  __syncthreads();

  if (tid < 32) {
    float a = 0.25f * (w_lds[tid] + w_lds[32 + tid] + w_lds[64 + tid] + w_lds[96 + tid]);
    out[1048576 + (size_t)t * 32 + tid] = a;
  }
  const int eo2 = tid * 2;
  float o0 = bo[eo2], o1 = bo[eo2 + 1];
  const uint4* cl2 = (const uint4*)ctx_lds;
  const half_t* wrow0 = wo16 + (size_t)eo2 * EDIM;
  const half_t* wrow1 = wrow0 + EDIM;
#pragma unroll 8
  for (int c = 0; c < 64; ++c) {
    uint4 cv = cl2[c];
    uint4 w0 = *(const uint4*)(wrow0 + c * 8);
    uint4 w1 = *(const uint4*)(wrow1 + c * 8);
    half2_t c0 = h2bc(cv.x), c1 = h2bc(cv.y), c2 = h2bc(cv.z), c3 = h2bc(cv.w);
    o0 = fdot2f(h2bc(w0.x), c0, o0);
    o0 = fdot2f(h2bc(w0.y), c1, o0);
    o0 = fdot2f(h2bc(w0.z), c2, o0);
    o0 = fdot2f(h2bc(w0.w), c3, o0);
    o1 = fdot2f(h2bc(w1.x), c0, o1);
    o1 = fdot2f(h2bc(w1.y), c1, o1);
    o1 = fdot2f(h2bc(w1.z), c2, o1);
    o1 = fdot2f(h2bc(w1.w), c3, o1);
  }
  out[(size_t)t * EDIM + eo2]     = o0;
  out[(size_t)t * EDIM + eo2 + 1] = o1;
}

// ---------------------------------------------------------------------------
extern "C" void kernel_launch(void* const* d_in, const int* in_sizes, int n_in,
                              void* d_out, int out_size, void* d_ws, size_t ws_size,
                              hipStream_t stream) {
  const float* x    = (const float*)d_in[0];
  const float* wihf = (const float*)d_in[1];
  const float* whhf = (const float*)d_in[2];
  const float* bf   = (const float*)d_in[3];
  const float* wihb = (const float*)d_in[4];
  const float* whhb = (const float*)d_in[5];
  const float* bbv  = (const float*)d_in[6];
  const float* te   = (const float*)d_in[7];
  const float* wq   = (const float*)d_in[8];
  const float* bq   = (const float*)d_in[9];
  const float* wk   = (const float*)d_in[10];
  const float* bk   = (const float*)d_in[11];
  const float* wvv  = (const float*)d_in[12];
  const float* bv   = (const float*)d_in[13];
  const float* wo   = (const float*)d_in[14];
  const float* bo   = (const float*)d_in[15];
  float* out = (float*)d_out;

  char* ws = (char*)d_ws;
  half_t* emb  = (half_t*)(ws + EMB_OFF);
  half_t* q_ws = (half_t*)(ws + Q_OFF);
  half_t* x16  = (half_t*)(ws + Q_OFF);
  half_t* wq16 = (half_t*)(ws + WQ_OFF);
  half_t* wk16 = (half_t*)(ws + WK_OFF);
  half_t* wv16 = (half_t*)(ws + WV_OFF);
  half_t* wo16 = (half_t*)(ws + WO_OFF);
  half_t* te16 = (half_t*)(ws + TE_OFF);

  convert_kernel<<<1808, 256, 0, stream>>>(wq, wk, wvv, wo, te, x,
                                           wq16, wk16, wv16, wo16, te16, x16);

  (void)hipFuncSetAttribute((const void*)lstm_kernel,
                            hipFuncAttributeMaxDynamicSharedMemorySize, LSTM_LDS_BYTES);
  lstm_kernel<<<64, 512, LSTM_LDS_BYTES, stream>>>(x16, wihf, whhf, bf, wihb, whhb, bbv, emb);

  qproj_kernel<<<64, 256, 0, stream>>>(emb, wq16, bq, q_ws);

  attn_kernel<<<2048, 256, 0, stream>>>(emb, q_ws, wk16, wv16, wo16, te16, bk, bv, bo, out);
}